// Round 1
// baseline (4917.778 us; speedup 1.0000x reference)
//
#include <hip/hip_runtime.h>
#include <cstdint>
#include <cstddef>

// DeltaNetMolecular: 5-layer EGNN + MLP head, fp32 correctness-first round.
// Key restructuring: concat(x_dst,x_src,ea)@W1 -> per-node projections A=x@Wdst(+b1),
// B=x@Wsrc (dense GEMMs), plus fused per-edge kernel that computes ea@Wea in LDS
// chunks, adds gathered A/B rows, silu, @W2, silu, LayerNorm(32), and scatter-adds
// into per-node message sums -- never materializing the [E,642] intermediate.

#define DEV __device__ __forceinline__

DEV float siluf(float x) { return x / (1.f + __expf(-x)); }

// ---------------------------------------------------------------- gather emb
__global__ __launch_bounds__(256) void k_gather(const int* __restrict__ atomids,
                                                const float* __restrict__ emb,
                                                float* __restrict__ feats_all, int N) {
  int idx = blockIdx.x * 256 + threadIdx.x;
  if (idx >= N * 128) return;
  int i = idx >> 7, j = idx & 127;
  feats_all[(size_t)i * 768 + j] = emb[atomids[i] * 128 + j];
}

// ------------------------------------------------------- edge dist + degree
__global__ __launch_bounds__(256) void k_edge_prep(const float* __restrict__ coords,
                                                   const int* __restrict__ ei, int E,
                                                   float* __restrict__ d_arr,
                                                   float* __restrict__ deg) {
  int e = blockIdx.x * 256 + threadIdx.x;
  if (e >= E) return;
  int s = ei[e], t = ei[E + e];
  float dx = coords[3 * s + 0] - coords[3 * t + 0];
  float dy = coords[3 * s + 1] - coords[3 * t + 1];
  float dz = coords[3 * s + 2] - coords[3 * t + 2];
  d_arr[e] = dx * dx + dy * dy + dz * dz;
  atomicAdd(&deg[t], 1.f);
}

// ------------------------------------------------------------- generic GEMM
// C[M,Nc] = act(actA(A[M,K]) @ W[K,Nc] + bias). Requires K%16==0, lda%4==0.
__global__ __launch_bounds__(256) void gemm_f32(
    const float* __restrict__ A, int lda,
    const float* __restrict__ W, int ldw,
    const float* __restrict__ bias,
    float* __restrict__ C, int ldc,
    int M, int Nc, int K, int actOut, int actA) {
  __shared__ float As[16][68];  // [k][m], padded
  __shared__ float Ws[16][64];  // [k][n]
  const int t = threadIdx.x;
  const int bm = blockIdx.x * 64;
  const int bn = blockIdx.y * 64;
  const int tx = t & 15, ty = t >> 4;
  const int am = t >> 2;          // 0..63 (A tile row)
  const int ak = (t & 3) << 2;    // 0,4,8,12
  const int wk = t >> 4;          // 0..15 (W tile row)
  const int wn = (t & 15) << 2;   // 0..60
  float acc[4][4] = {};
  for (int k0 = 0; k0 < K; k0 += 16) {
    float4 av = make_float4(0.f, 0.f, 0.f, 0.f);
    if (bm + am < M)
      av = *(const float4*)(A + (size_t)(bm + am) * lda + k0 + ak);
    if (actA) { av.x = siluf(av.x); av.y = siluf(av.y); av.z = siluf(av.z); av.w = siluf(av.w); }
    As[ak + 0][am] = av.x; As[ak + 1][am] = av.y;
    As[ak + 2][am] = av.z; As[ak + 3][am] = av.w;
    const float* wrow = W + (size_t)(k0 + wk) * ldw + bn + wn;
#pragma unroll
    for (int u = 0; u < 4; ++u)
      Ws[wk][wn + u] = (bn + wn + u < Nc) ? wrow[u] : 0.f;
    __syncthreads();
#pragma unroll
    for (int kk = 0; kk < 16; ++kk) {
      float a[4], b[4];
#pragma unroll
      for (int i = 0; i < 4; ++i) a[i] = As[kk][ty * 4 + i];
#pragma unroll
      for (int j = 0; j < 4; ++j) b[j] = Ws[kk][tx * 4 + j];
#pragma unroll
      for (int i = 0; i < 4; ++i)
#pragma unroll
        for (int j = 0; j < 4; ++j) acc[i][j] += a[i] * b[j];
    }
    __syncthreads();
  }
#pragma unroll
  for (int i = 0; i < 4; ++i) {
    int r = bm + ty * 4 + i;
    if (r >= M) continue;
#pragma unroll
    for (int j = 0; j < 4; ++j) {
      int c = bn + tx * 4 + j;
      if (c >= Nc) continue;
      float v = acc[i][j] + (bias ? bias[c] : 0.f);
      if (actOut) v = siluf(v);
      C[(size_t)r * ldc + c] = v;
    }
  }
}

// -------------------------------------------------------- fused edge kernel
// Per block: 64 edges. h = silu(A[dst]+B[src]+ea@Wea); m = silu(h@W2+b2);
// m = LN(m); atomicAdd into msum[dst]. Never materializes h globally.
__global__ __launch_bounds__(256) void k_edge_fused(
    const float* __restrict__ Ab, const float* __restrict__ Bb,  // [N,644] padded
    const int* __restrict__ ei, int E,
    const float* __restrict__ d_arr,
    const float* __restrict__ Wea,  // [65,642]
    const float* __restrict__ W2,   // [642,32]
    const float* __restrict__ b2,   // [32]
    const float* __restrict__ eng, const float* __restrict__ enb,
    float* __restrict__ msum) {
  __shared__ float sEAT[65 * 64];  // ea transposed [q][edge]
  __shared__ float sW[65 * 64];    // Wea chunk [q][j]
  __shared__ float sW2[64 * 32];   // W2 chunk [j][m]
  __shared__ float sH[64 * 65];    // h tile [edge][j], stride 65
  __shared__ int sSrc[64], sDst[64];
  __shared__ float sD[64], sMu[64], sRstd[64];

  const int t = threadIdx.x;
  const int e0 = blockIdx.x * 64;
  if (t < 64) {
    int e = e0 + t;
    sSrc[t] = (e < E) ? ei[e] : 0;
    sDst[t] = (e < E) ? ei[E + e] : 0;
    sD[t] = (e < E) ? d_arr[e] : 0.f;
  }
  __syncthreads();
  for (int idx = t; idx < 65 * 64; idx += 256) {
    int q = idx >> 6, e = idx & 63;
    float d = sD[e];
    float v;
    if (q < 32)      v = sinf(d * exp2f(-(float)q));
    else if (q < 64) v = cosf(d * exp2f(-(float)(q - 32)));
    else             v = d;
    sEAT[idx] = v;
  }
  const int a1 = t & 15, b1 = t >> 4;    // gemm1: edges 4*a1.., cols 4*b1..
  const int a2 = t & 31, b2i = t >> 5;   // gemm2: edges 2*a2.., mcols 4*b2i..
  float mAcc[2][4] = {{0, 0, 0, 0}, {0, 0, 0, 0}};
  const float4* sEAT4 = (const float4*)sEAT;
  const float4* sW4 = (const float4*)sW;
  const float4* sW24 = (const float4*)sW2;

  for (int c = 0; c < 11; ++c) {
    const int jb = c * 64;
    __syncthreads();  // protects prior-iter reads (and sEAT build on iter 0)
    for (int idx = t; idx < 65 * 64; idx += 256) {
      int q = idx >> 6, j = idx & 63;
      int col = jb + j;
      sW[idx] = (col < 642) ? Wea[q * 642 + col] : 0.f;
    }
    for (int idx = t; idx < 64 * 32; idx += 256) {
      int r = idx >> 5, j2 = idx & 31;
      int col = jb + r;
      sW2[idx] = (col < 642) ? W2[col * 32 + j2] : 0.f;
    }
    __syncthreads();
    // prefetch gathered A[dst]+B[src] for this thread's 4 edges x 4 cols
    const int ecol = jb + 4 * b1;
    float ab[4][4];
#pragma unroll
    for (int i = 0; i < 4; ++i) {
      int e = 4 * a1 + i;
      const float* ap = Ab + (size_t)sDst[e] * 644;
      const float* bp = Bb + (size_t)sSrc[e] * 644;
      if (ecol + 3 < 642) {
        float4 va = *(const float4*)(ap + ecol);
        float4 vb = *(const float4*)(bp + ecol);
        ab[i][0] = va.x + vb.x; ab[i][1] = va.y + vb.y;
        ab[i][2] = va.z + vb.z; ab[i][3] = va.w + vb.w;
      } else {
#pragma unroll
        for (int u = 0; u < 4; ++u) {
          int cc = ecol + u;
          ab[i][u] = (cc < 642) ? (ap[cc] + bp[cc]) : 0.f;
        }
      }
    }
    // GEMM1: h = ea @ Wea_chunk
    float h[4][4] = {};
    for (int q = 0; q < 65; ++q) {
      float4 av = sEAT4[q * 16 + a1];
      float4 wv = sW4[q * 16 + b1];
      float aa[4] = {av.x, av.y, av.z, av.w};
      float ww[4] = {wv.x, wv.y, wv.z, wv.w};
#pragma unroll
      for (int i = 0; i < 4; ++i)
#pragma unroll
        for (int j = 0; j < 4; ++j) h[i][j] += aa[i] * ww[j];
    }
#pragma unroll
    for (int i = 0; i < 4; ++i) {
      int e = 4 * a1 + i;
#pragma unroll
      for (int j = 0; j < 4; ++j)
        sH[e * 65 + 4 * b1 + j] = siluf(h[i][j] + ab[i][j]);
    }
    __syncthreads();
    // GEMM2: mAcc += h_chunk @ W2_chunk
    for (int kk = 0; kk < 64; ++kk) {
      float h0 = sH[(2 * a2) * 65 + kk];
      float h1 = sH[(2 * a2 + 1) * 65 + kk];
      float4 w = sW24[kk * 8 + b2i];
      mAcc[0][0] += h0 * w.x; mAcc[0][1] += h0 * w.y;
      mAcc[0][2] += h0 * w.z; mAcc[0][3] += h0 * w.w;
      mAcc[1][0] += h1 * w.x; mAcc[1][1] += h1 * w.y;
      mAcc[1][2] += h1 * w.z; mAcc[1][3] += h1 * w.w;
    }
  }
  // bias + silu + stage m to LDS (alias sW, stride 33 to dodge bank conflicts)
  float* sM = sW;
  __syncthreads();
#pragma unroll
  for (int i = 0; i < 2; ++i) {
    int e = 2 * a2 + i;
#pragma unroll
    for (int j = 0; j < 4; ++j) {
      int col = 4 * b2i + j;
      sM[e * 33 + col] = siluf(mAcc[i][j] + b2[col]);
    }
  }
  __syncthreads();
  if (t < 64) {
    float s = 0.f, ss = 0.f;
#pragma unroll
    for (int j = 0; j < 32; ++j) {
      float x = sM[t * 33 + j];
      s += x; ss += x * x;
    }
    float mu = s * (1.f / 32.f);
    float var = ss * (1.f / 32.f) - mu * mu;
    sMu[t] = mu;
    sRstd[t] = rsqrtf(var + 1e-5f);
  }
  __syncthreads();
#pragma unroll
  for (int i = 0; i < 2; ++i) {
    int e = 2 * a2 + i;
    if (e0 + e < E) {
      int drow = sDst[e];
      float mu = sMu[e], rs = sRstd[e];
#pragma unroll
      for (int j = 0; j < 4; ++j) {
        int col = 4 * b2i + j;
        float val = (sM[e * 33 + col] - mu) * rs * eng[col] + enb[col];
        atomicAdd(&msum[(size_t)drow * 32 + col], val);
      }
    }
  }
}

// --------------------------------------------- node-side LN + concat builder
__global__ __launch_bounds__(256) void k_node_ln(
    const float* __restrict__ msum, const float* __restrict__ deg,
    const float* __restrict__ featsAll, int k,
    const float* __restrict__ n1g, const float* __restrict__ n1b,
    const float* __restrict__ eng, const float* __restrict__ enb,
    float* __restrict__ hcat, int N) {
  int node = blockIdx.x * 4 + (threadIdx.x >> 6);
  int lane = threadIdx.x & 63;
  if (node >= N) return;
  const float* fr = featsAll + (size_t)node * 768 + k * 128;
  float x0 = fr[lane], x1 = fr[64 + lane];
  float s = x0 + x1;
#pragma unroll
  for (int m = 1; m < 64; m <<= 1) s += __shfl_xor(s, m, 64);
  float mu = s * (1.f / 128.f);
  float d0 = x0 - mu, d1 = x1 - mu;
  float v = d0 * d0 + d1 * d1;
#pragma unroll
  for (int m = 1; m < 64; m <<= 1) v += __shfl_xor(v, m, 64);
  float rstd = rsqrtf(v * (1.f / 128.f) + 1e-5f);
  float* hr = hcat + (size_t)node * 160;
  hr[lane] = d0 * rstd * n1g[lane] + n1b[lane];
  hr[64 + lane] = d1 * rstd * n1g[64 + lane] + n1b[64 + lane];
  // m_i = LN(msum/deg) over 32
  float dg = fmaxf(deg[node], 1.f);
  int col = lane & 31;
  float y = msum[(size_t)node * 32 + col] / dg;
  float sy = y;
#pragma unroll
  for (int m = 1; m < 32; m <<= 1) sy += __shfl_xor(sy, m, 32);
  float mu2 = sy * (1.f / 32.f);
  float dy = y - mu2;
  float vy = dy * dy;
#pragma unroll
  for (int m = 1; m < 32; m <<= 1) vy += __shfl_xor(vy, m, 32);
  float rstd2 = rsqrtf(vy * (1.f / 32.f) + 1e-5f);
  if (lane < 32) hr[128 + col] = dy * rstd2 * eng[col] + enb[col];
}

// ------------------------------------------------ node residual + final LN
__global__ __launch_bounds__(256) void k_node_resid(
    const float* __restrict__ t2, float* __restrict__ featsAll, int k,
    const float* __restrict__ n2g, const float* __restrict__ n2b, int N) {
  int node = blockIdx.x * 4 + (threadIdx.x >> 6);
  int lane = threadIdx.x & 63;
  if (node >= N) return;
  const float* tr = t2 + (size_t)node * 128;
  float x0 = tr[lane], x1 = tr[64 + lane];
  float s = x0 + x1;
#pragma unroll
  for (int m = 1; m < 64; m <<= 1) s += __shfl_xor(s, m, 64);
  float mu = s * (1.f / 128.f);
  float d0 = x0 - mu, d1 = x1 - mu;
  float v = d0 * d0 + d1 * d1;
#pragma unroll
  for (int m = 1; m < 64; m <<= 1) v += __shfl_xor(v, m, 64);
  float rstd = rsqrtf(v * (1.f / 128.f) + 1e-5f);
  const float* fk = featsAll + (size_t)node * 768 + k * 128;
  float* fo = featsAll + (size_t)node * 768 + (k + 1) * 128;
  fo[lane] = fk[lane] + d0 * rstd * n2g[lane] + n2b[lane];
  fo[64 + lane] = fk[64 + lane] + d1 * rstd * n2g[64 + lane] + n2b[64 + lane];
}

// ----------------------------------------------------------- graph pooling
__global__ __launch_bounds__(256) void k_pool(const float* __restrict__ f,
                                              const int* __restrict__ batch,
                                              float* __restrict__ gsum,
                                              float* __restrict__ gcnt, int N) {
  int idx = blockIdx.x * 256 + threadIdx.x;
  if (idx >= N * 256) return;
  int i = idx >> 8, j = idx & 255;
  int b = batch[i];
  atomicAdd(&gsum[b * 256 + j], f[idx]);
  if (j == 0) atomicAdd(&gcnt[b], 1.f);
}

__global__ void k_gdiv(float* gsum, const float* gcnt) {
  int b = blockIdx.x, j = threadIdx.x;
  gsum[b * 256 + j] /= fmaxf(gcnt[b], 1.f);
}

__global__ void k_gout(const float* __restrict__ g2, const float* __restrict__ gW2,
                       const float* __restrict__ gb2, float* __restrict__ out) {
  int b = threadIdx.x;
  if (b >= 64) return;
  float s = gb2[0];
  for (int j = 0; j < 256; ++j) s += g2[b * 256 + j] * gW2[j];
  out[b] = s;
}

// ------------------------------------------------------------------- launch
extern "C" void kernel_launch(void* const* d_in, const int* in_sizes, int n_in,
                              void* d_out, int out_size, void* d_ws, size_t ws_size,
                              hipStream_t stream) {
  const float* coords = (const float*)d_in[0];
  const int* atomids = (const int*)d_in[1];
  const int* ei = (const int*)d_in[2];
  const int* batch = (const int*)d_in[3];
  const float* emb = (const float*)d_in[5];
  const float* keW1 = (const float*)d_in[6];
  const float* keb1 = (const float*)d_in[7];
  const float* keW2 = (const float*)d_in[8];
  const float* keb2 = (const float*)d_in[9];
  const float* keng = (const float*)d_in[10];
  const float* kenb = (const float*)d_in[11];
  const float* kn1g = (const float*)d_in[12];
  const float* kn1b = (const float*)d_in[13];
  const float* knW1 = (const float*)d_in[14];
  const float* knb1 = (const float*)d_in[15];
  const float* knW2 = (const float*)d_in[16];
  const float* knb2 = (const float*)d_in[17];
  const float* kn2g = (const float*)d_in[18];
  const float* kn2b = (const float*)d_in[19];
  const float* fW0 = (const float*)d_in[20];
  const float* fb0 = (const float*)d_in[21];
  const float* fW1 = (const float*)d_in[22];
  const float* fb1 = (const float*)d_in[23];
  const float* fW2 = (const float*)d_in[24];
  const float* fb2 = (const float*)d_in[25];
  const float* gW0 = (const float*)d_in[26];
  const float* gb0 = (const float*)d_in[27];
  const float* gW1 = (const float*)d_in[28];
  const float* gb1 = (const float*)d_in[29];
  const float* gW2 = (const float*)d_in[30];
  const float* gb2 = (const float*)d_in[31];

  const int N = in_sizes[0] / 3;
  const int E = in_sizes[2] / 2;

  size_t off = 0;
  auto alloc = [&](size_t n) {
    float* p = (float*)d_ws + off;
    off += (n + 63) & ~(size_t)63;
    return p;
  };
  float* feats_all = alloc((size_t)N * 768);  // feat_list slices 0..5
  float* d_arr = alloc(E);
  float* deg = alloc(N);
  float* msum = alloc((size_t)N * 32);
  float* Abuf = alloc((size_t)N * 644);  // padded stride 644
  float* Bbuf = alloc((size_t)N * 644);
  float* gsum = alloc(64 * 256);
  float* gcnt = alloc(64);
  float* g1 = alloc(64 * 256);
  float* g2 = alloc(64 * 256);
  // aliases (A/B dead when these come alive within a layer)
  float* hcat = Abuf;                          // N x 160
  float* t1 = Abuf + (size_t)N * 160;          // N x 256
  float* t2 = Abuf + (size_t)N * 416;          // N x 128
  float* f1 = Bbuf;                            // N x 256 (after layers)
  float* f2 = Bbuf + (size_t)N * 256;          // N x 256

  k_gather<<<(N * 128 + 255) / 256, 256, 0, stream>>>(atomids, emb, feats_all, N);
  hipMemsetAsync(deg, 0, (size_t)N * sizeof(float), stream);
  k_edge_prep<<<(E + 255) / 256, 256, 0, stream>>>(coords, ei, E, d_arr, deg);

  for (int k = 0; k < 5; ++k) {
    const float* W1k = keW1 + (size_t)k * 321 * 642;
    gemm_f32<<<dim3((N + 63) / 64, 11), 256, 0, stream>>>(
        feats_all + k * 128, 768, W1k, 642, keb1 + k * 642, Abuf, 644, N, 642, 128, 0, 0);
    gemm_f32<<<dim3((N + 63) / 64, 11), 256, 0, stream>>>(
        feats_all + k * 128, 768, W1k + 128 * 642, 642, nullptr, Bbuf, 644, N, 642, 128, 0, 0);
    hipMemsetAsync(msum, 0, (size_t)N * 32 * sizeof(float), stream);
    k_edge_fused<<<(E + 63) / 64, 256, 0, stream>>>(
        Abuf, Bbuf, ei, E, d_arr, W1k + 256 * 642, keW2 + (size_t)k * 642 * 32,
        keb2 + k * 32, keng + k * 32, kenb + k * 32, msum);
    k_node_ln<<<(N + 3) / 4, 256, 0, stream>>>(
        msum, deg, feats_all, k, kn1g + k * 128, kn1b + k * 128,
        keng + k * 32, kenb + k * 32, hcat, N);
    gemm_f32<<<dim3((N + 63) / 64, 4), 256, 0, stream>>>(
        hcat, 160, knW1 + (size_t)k * 160 * 256, 256, knb1 + k * 256, t1, 256, N, 256, 160, 1, 0);
    gemm_f32<<<dim3((N + 63) / 64, 2), 256, 0, stream>>>(
        t1, 256, knW2 + (size_t)k * 256 * 128, 128, knb2 + k * 128, t2, 128, N, 128, 256, 0, 0);
    k_node_resid<<<(N + 3) / 4, 256, 0, stream>>>(
        t2, feats_all, k, kn2g + k * 128, kn2b + k * 128, N);
  }

  gemm_f32<<<dim3((N + 63) / 64, 4), 256, 0, stream>>>(
      feats_all, 768, fW0, 256, fb0, f1, 256, N, 256, 768, 1, 1);
  gemm_f32<<<dim3((N + 63) / 64, 4), 256, 0, stream>>>(
      f1, 256, fW1, 256, fb1, f2, 256, N, 256, 256, 1, 0);
  gemm_f32<<<dim3((N + 63) / 64, 4), 256, 0, stream>>>(
      f2, 256, fW2, 256, fb2, f1, 256, N, 256, 256, 1, 0);

  hipMemsetAsync(gsum, 0, 64 * 256 * sizeof(float), stream);
  hipMemsetAsync(gcnt, 0, 64 * sizeof(float), stream);
  k_pool<<<(N * 256 + 255) / 256, 256, 0, stream>>>(f1, batch, gsum, gcnt, N);
  k_gdiv<<<64, 256, 0, stream>>>(gsum, gcnt);
  gemm_f32<<<dim3(1, 4), 256, 0, stream>>>(gsum, 256, gW0, 256, gb0, g1, 256, 64, 256, 256, 1, 0);
  gemm_f32<<<dim3(1, 4), 256, 0, stream>>>(g1, 256, gW1, 256, gb1, g2, 256, 64, 256, 256, 1, 0);
  k_gout<<<1, 64, 0, stream>>>(g2, gW2, gb2, (float*)d_out);
}

// Round 2
// 2917.060 us; speedup vs baseline: 1.6859x; 1.6859x over previous
//
#include <hip/hip_runtime.h>
#include <cstdint>
#include <cstddef>

// DeltaNetMolecular R2: bf16x3 (hi/lo split) MFMA everywhere.
// concat(x_dst,x_src,ea)@W1 -> A=x@Wdst+b1, B=x@Wsrc dense MFMA GEMMs + fused
// edge kernel (ea@Wea via MFMA with register-resident A-frags, +gathered A/B,
// silu, @W2 via MFMA, LN, scatter-mean) that never materializes [E,642].
// All weights prepacked to transposed hi/lo bf16 [n][k] for direct B-frag loads.

#define DEV __device__ __forceinline__

typedef __attribute__((ext_vector_type(8))) short bf16x8;
typedef __attribute__((ext_vector_type(4))) float f32x4;

DEV float siluf(float x) { return x / (1.f + __expf(-x)); }

DEV unsigned short f2bf(float f) {
  unsigned u = __float_as_uint(f);
  unsigned r = u + 0x7FFFu + ((u >> 16) & 1u);
  return (unsigned short)(r >> 16);
}
DEV float bf2f(unsigned short h) { return __uint_as_float(((unsigned)h) << 16); }

DEV f32x4 mfma16(bf16x8 a, bf16x8 b, f32x4 c) {
  return __builtin_amdgcn_mfma_f32_16x16x32_bf16(a, b, c, 0, 0, 0);
}

// ---------------------------------------------------------------- gather emb
__global__ __launch_bounds__(256) void k_gather(const int* __restrict__ atomids,
                                                const float* __restrict__ emb,
                                                float* __restrict__ feats_all, int N) {
  int idx = blockIdx.x * 256 + threadIdx.x;
  if (idx >= N * 128) return;
  int i = idx >> 7, j = idx & 127;
  feats_all[(size_t)i * 768 + j] = emb[atomids[i] * 128 + j];
}

// ------------------------------------------------------- edge dist + degree
__global__ __launch_bounds__(256) void k_edge_prep(const float* __restrict__ coords,
                                                   const int* __restrict__ ei, int E,
                                                   float* __restrict__ d_arr,
                                                   float* __restrict__ deg) {
  int e = blockIdx.x * 256 + threadIdx.x;
  if (e >= E) return;
  int s = ei[e], t = ei[E + e];
  float dx = coords[3 * s + 0] - coords[3 * t + 0];
  float dy = coords[3 * s + 1] - coords[3 * t + 1];
  float dz = coords[3 * s + 2] - coords[3 * t + 2];
  d_arr[e] = dx * dx + dy * dy + dz * dz;
  atomicAdd(&deg[t], 1.f);
}

// ----------------------------------------------------- weight prepack (hi/lo)
// out[n][kk] = W[kk*ldw + n] (zero-padded), split into hi/lo bf16.
// blockIdx.y = layer; W += layer*wStride, outputs += layer*oStride.
__global__ __launch_bounds__(256) void k_prepack(
    const float* __restrict__ W, size_t wStride, int ldw,
    int K, int Kpad, int Ncols, int Npad,
    unsigned short* __restrict__ hi, unsigned short* __restrict__ lo, size_t oStride) {
  int idx = blockIdx.x * 256 + threadIdx.x;
  int total = Npad * Kpad;
  if (idx >= total) return;
  W += blockIdx.y * wStride;
  hi += blockIdx.y * oStride;
  lo += blockIdx.y * oStride;
  int n = idx / Kpad, k = idx - n * Kpad;
  float v = (n < Ncols && k < K) ? W[(size_t)k * ldw + n] : 0.f;
  unsigned short h = f2bf(v);
  hi[idx] = h;
  lo[idx] = f2bf(v - bf2f(h));
}

// ------------------------------------------------- generic bf16x3 MFMA GEMM
// C[M,Ncols] = act(actA(A) @ Wt^T + bias); Wt prepacked [Npad][Kpad] hi/lo,
// Npad = gridDim.y*64 (zero-filled). K % 32 == 0, lda % 4 == 0.
__global__ __launch_bounds__(256) void gemm_mfma(
    const float* __restrict__ A, int lda,
    const unsigned short* __restrict__ Bhi, const unsigned short* __restrict__ Blo,
    int Kpad, const float* __restrict__ bias,
    float* __restrict__ C, int ldc,
    int M, int Ncols, int K, int actOut, int actA) {
  const int t = threadIdx.x;
  const int wave = t >> 6, lane = t & 63;
  const int nl = lane & 15, quad = lane >> 4;
  const int bm = blockIdx.x * 64 + wave * 16;
  const int bn = blockIdx.y * 64;
  const int row = bm + nl;
  f32x4 zero = {0.f, 0.f, 0.f, 0.f};
  f32x4 acc[4] = {zero, zero, zero, zero};
  for (int kb = 0; kb < K; kb += 32) {
    bf16x8 ah, al;
    float av[8];
    if (row < M) {
      const float* ap = A + (size_t)row * lda + kb + quad * 8;
      f32x4 v0 = *(const f32x4*)ap;
      f32x4 v1 = *(const f32x4*)(ap + 4);
      av[0] = v0.x; av[1] = v0.y; av[2] = v0.z; av[3] = v0.w;
      av[4] = v1.x; av[5] = v1.y; av[6] = v1.z; av[7] = v1.w;
      if (actA) {
#pragma unroll
        for (int j = 0; j < 8; ++j) av[j] = siluf(av[j]);
      }
    } else {
#pragma unroll
      for (int j = 0; j < 8; ++j) av[j] = 0.f;
    }
#pragma unroll
    for (int j = 0; j < 8; ++j) {
      unsigned short h = f2bf(av[j]);
      ah[j] = (short)h;
      al[j] = (short)f2bf(av[j] - bf2f(h));
    }
#pragma unroll
    for (int tn = 0; tn < 4; ++tn) {
      size_t boff = (size_t)(bn + tn * 16 + nl) * Kpad + kb + quad * 8;
      bf16x8 bh = *(const bf16x8*)(Bhi + boff);
      bf16x8 bl = *(const bf16x8*)(Blo + boff);
      acc[tn] = mfma16(ah, bh, acc[tn]);
      acc[tn] = mfma16(ah, bl, acc[tn]);
      acc[tn] = mfma16(al, bh, acc[tn]);
    }
  }
#pragma unroll
  for (int tn = 0; tn < 4; ++tn) {
    int c = bn + tn * 16 + nl;
    if (c >= Ncols) continue;
    float bv = bias ? bias[c] : 0.f;
#pragma unroll
    for (int r = 0; r < 4; ++r) {
      int rr = bm + quad * 4 + r;
      if (rr >= M) continue;
      float v = acc[tn][r] + bv;
      if (actOut) v = siluf(v);
      C[(size_t)rr * ldc + c] = v;
    }
  }
}

// ------------------------------------------------- fused edge kernel (MFMA)
// Block = 64 edges, 4 waves. h = silu(ea@Wea + A[dst]+B[src]+d*Wea_row64);
// m = silu(h@W2+b2); LN(m); atomicAdd msum[dst].
__global__ __launch_bounds__(256) void k_edge_mfma(
    const float* __restrict__ Ab, const float* __restrict__ Bb,  // [N,644]
    const int* __restrict__ ei, int E,
    const float* __restrict__ d_arr,
    const unsigned short* __restrict__ WeaThi, const unsigned short* __restrict__ WeaTlo, // [704][64]
    const float* __restrict__ Wea64,  // W1 row 320, [642]
    const unsigned short* __restrict__ W2Thi, const unsigned short* __restrict__ W2Tlo,   // [32][704]
    const float* __restrict__ b2,
    const float* __restrict__ eng, const float* __restrict__ enb,
    float* __restrict__ msum) {
  __shared__ float sAB[64 * 68];
  __shared__ float sH[64 * 76];
  __shared__ float sD[64];
  __shared__ int sSrc[64], sDst[64];

  const int t = threadIdx.x;
  const int wave = t >> 6, lane = t & 63;
  const int nl = lane & 15, quad = lane >> 4;
  const int e0 = blockIdx.x * 64;

  if (t < 64) {
    int e = e0 + t;
    sSrc[t] = (e < E) ? ei[e] : 0;
    sDst[t] = (e < E) ? ei[E + e] : 0;
    sD[t] = (e < E) ? d_arr[e] : 0.f;
  }
  __syncthreads();

  // ea A-frags (register-resident for entire kernel)
  bf16x8 eaHi[2], eaLo[2];
  {
    float d = sD[wave * 16 + nl];
#pragma unroll
    for (int ks = 0; ks < 2; ++ks) {
#pragma unroll
      for (int j = 0; j < 8; ++j) {
        int k = ks * 32 + quad * 8 + j;
        float arg = d * exp2f(-(float)(k & 31));
        float v = (k < 32) ? sinf(arg) : cosf(arg);
        unsigned short h = f2bf(v);
        eaHi[ks][j] = (short)h;
        eaLo[ks][j] = (short)f2bf(v - bf2f(h));
      }
    }
  }

  f32x4 zero = {0.f, 0.f, 0.f, 0.f};
  f32x4 macc[2] = {zero, zero};

  for (int c = 0; c < 11; ++c) {
    const int jb = c * 64;
    __syncthreads();
    // stage sAB = A[dst]+B[src]+d*Wea64 for this 64-col chunk
    for (int idx = t; idx < 64 * 16; idx += 256) {
      int e = idx >> 4, p = idx & 15;
      int col = jb + p * 4;
      float d = sD[e];
      const float* ap = Ab + (size_t)sDst[e] * 644 + col;
      const float* bp = Bb + (size_t)sSrc[e] * 644 + col;
      float o[4];
      if (col + 3 < 642) {
        f32x4 va = *(const f32x4*)ap;
        f32x4 vb = *(const f32x4*)bp;
        f32x4 vw = *(const f32x4*)(Wea64 + col);
        o[0] = va.x + vb.x + d * vw.x;
        o[1] = va.y + vb.y + d * vw.y;
        o[2] = va.z + vb.z + d * vw.z;
        o[3] = va.w + vb.w + d * vw.w;
      } else {
#pragma unroll
        for (int u = 0; u < 4; ++u)
          o[u] = (col + u < 642) ? (ap[u] + bp[u] + d * Wea64[col + u]) : 0.f;
      }
#pragma unroll
      for (int u = 0; u < 4; ++u) sAB[e * 68 + p * 4 + u] = o[u];
    }
    __syncthreads();
    // GEMM1: ea[64x64] @ Wea_chunk[64x64]
    f32x4 acc1[4] = {zero, zero, zero, zero};
#pragma unroll
    for (int tn = 0; tn < 4; ++tn) {
      size_t base = (size_t)(jb + tn * 16 + nl) * 64 + quad * 8;
#pragma unroll
      for (int ks = 0; ks < 2; ++ks) {
        bf16x8 bh = *(const bf16x8*)(WeaThi + base + ks * 32);
        bf16x8 bl = *(const bf16x8*)(WeaTlo + base + ks * 32);
        acc1[tn] = mfma16(eaHi[ks], bh, acc1[tn]);
        acc1[tn] = mfma16(eaHi[ks], bl, acc1[tn]);
        acc1[tn] = mfma16(eaLo[ks], bh, acc1[tn]);
      }
    }
    // + gathered, silu, -> sH (fp32, stride 76)
#pragma unroll
    for (int tn = 0; tn < 4; ++tn) {
#pragma unroll
      for (int r = 0; r < 4; ++r) {
        int e = wave * 16 + quad * 4 + r;
        int colc = tn * 16 + nl;
        sH[e * 76 + colc] = siluf(acc1[tn][r] + sAB[e * 68 + colc]);
      }
    }
    __syncthreads();
    // GEMM2: h[64x64] @ W2_chunk[64x32], accumulate across chunks
#pragma unroll
    for (int ks = 0; ks < 2; ++ks) {
      const float* hp = &sH[(wave * 16 + nl) * 76 + ks * 32 + quad * 8];
      f32x4 h0 = *(const f32x4*)hp;
      f32x4 h1 = *(const f32x4*)(hp + 4);
      float hv[8] = {h0.x, h0.y, h0.z, h0.w, h1.x, h1.y, h1.z, h1.w};
      bf16x8 ah, al;
#pragma unroll
      for (int j = 0; j < 8; ++j) {
        unsigned short hh = f2bf(hv[j]);
        ah[j] = (short)hh;
        al[j] = (short)f2bf(hv[j] - bf2f(hh));
      }
#pragma unroll
      for (int tn = 0; tn < 2; ++tn) {
        size_t base = (size_t)(tn * 16 + nl) * 704 + jb + ks * 32 + quad * 8;
        bf16x8 bh = *(const bf16x8*)(W2Thi + base);
        bf16x8 bl = *(const bf16x8*)(W2Tlo + base);
        macc[tn] = mfma16(ah, bh, macc[tn]);
        macc[tn] = mfma16(ah, bl, macc[tn]);
        macc[tn] = mfma16(al, bh, macc[tn]);
      }
    }
  }
  // epilogue: bias + silu + LN(32) via width-16 shuffles + atomic scatter
  float g0 = eng[nl], g1v = eng[16 + nl], bb0 = enb[nl], bb1 = enb[16 + nl];
  float bi0 = b2[nl], bi1 = b2[16 + nl];
#pragma unroll
  for (int r = 0; r < 4; ++r) {
    float v0 = siluf(macc[0][r] + bi0);
    float v1 = siluf(macc[1][r] + bi1);
    float s = v0 + v1;
    float ss = v0 * v0 + v1 * v1;
#pragma unroll
    for (int m = 1; m < 16; m <<= 1) {
      s += __shfl_xor(s, m, 16);
      ss += __shfl_xor(ss, m, 16);
    }
    float mu = s * (1.f / 32.f);
    float var = ss * (1.f / 32.f) - mu * mu;
    float rs = rsqrtf(var + 1e-5f);
    int eb = wave * 16 + quad * 4 + r;
    if (e0 + eb < E) {
      int dn = sDst[eb];
      atomicAdd(&msum[(size_t)dn * 32 + nl], (v0 - mu) * rs * g0 + bb0);
      atomicAdd(&msum[(size_t)dn * 32 + 16 + nl], (v1 - mu) * rs * g1v + bb1);
    }
  }
}

// --------------------------------------------- node-side LN + concat builder
__global__ __launch_bounds__(256) void k_node_ln(
    const float* __restrict__ msum, const float* __restrict__ deg,
    const float* __restrict__ featsAll, int k,
    const float* __restrict__ n1g, const float* __restrict__ n1b,
    const float* __restrict__ eng, const float* __restrict__ enb,
    float* __restrict__ hcat, int N) {
  int node = blockIdx.x * 4 + (threadIdx.x >> 6);
  int lane = threadIdx.x & 63;
  if (node >= N) return;
  const float* fr = featsAll + (size_t)node * 768 + k * 128;
  float x0 = fr[lane], x1 = fr[64 + lane];
  float s = x0 + x1;
#pragma unroll
  for (int m = 1; m < 64; m <<= 1) s += __shfl_xor(s, m, 64);
  float mu = s * (1.f / 128.f);
  float d0 = x0 - mu, d1 = x1 - mu;
  float v = d0 * d0 + d1 * d1;
#pragma unroll
  for (int m = 1; m < 64; m <<= 1) v += __shfl_xor(v, m, 64);
  float rstd = rsqrtf(v * (1.f / 128.f) + 1e-5f);
  float* hr = hcat + (size_t)node * 160;
  hr[lane] = d0 * rstd * n1g[lane] + n1b[lane];
  hr[64 + lane] = d1 * rstd * n1g[64 + lane] + n1b[64 + lane];
  float dg = fmaxf(deg[node], 1.f);
  int col = lane & 31;
  float y = msum[(size_t)node * 32 + col] / dg;
  float sy = y;
#pragma unroll
  for (int m = 1; m < 32; m <<= 1) sy += __shfl_xor(sy, m, 32);
  float mu2 = sy * (1.f / 32.f);
  float dy = y - mu2;
  float vy = dy * dy;
#pragma unroll
  for (int m = 1; m < 32; m <<= 1) vy += __shfl_xor(vy, m, 32);
  float rstd2 = rsqrtf(vy * (1.f / 32.f) + 1e-5f);
  if (lane < 32) hr[128 + col] = dy * rstd2 * eng[col] + enb[col];
}

// ------------------------------------------------ node residual + final LN
__global__ __launch_bounds__(256) void k_node_resid(
    const float* __restrict__ t2, float* __restrict__ featsAll, int k,
    const float* __restrict__ n2g, const float* __restrict__ n2b, int N) {
  int node = blockIdx.x * 4 + (threadIdx.x >> 6);
  int lane = threadIdx.x & 63;
  if (node >= N) return;
  const float* tr = t2 + (size_t)node * 128;
  float x0 = tr[lane], x1 = tr[64 + lane];
  float s = x0 + x1;
#pragma unroll
  for (int m = 1; m < 64; m <<= 1) s += __shfl_xor(s, m, 64);
  float mu = s * (1.f / 128.f);
  float d0 = x0 - mu, d1 = x1 - mu;
  float v = d0 * d0 + d1 * d1;
#pragma unroll
  for (int m = 1; m < 64; m <<= 1) v += __shfl_xor(v, m, 64);
  float rstd = rsqrtf(v * (1.f / 128.f) + 1e-5f);
  const float* fk = featsAll + (size_t)node * 768 + k * 128;
  float* fo = featsAll + (size_t)node * 768 + (k + 1) * 128;
  fo[lane] = fk[lane] + d0 * rstd * n2g[lane] + n2b[lane];
  fo[64 + lane] = fk[64 + lane] + d1 * rstd * n2g[64 + lane] + n2b[64 + lane];
}

// ----------------------------------------------------------- graph pooling
__global__ __launch_bounds__(256) void k_pool(const float* __restrict__ f,
                                              const int* __restrict__ batch,
                                              float* __restrict__ gsum,
                                              float* __restrict__ gcnt, int N) {
  int idx = blockIdx.x * 256 + threadIdx.x;
  if (idx >= N * 256) return;
  int i = idx >> 8, j = idx & 255;
  int b = batch[i];
  atomicAdd(&gsum[b * 256 + j], f[idx]);
  if (j == 0) atomicAdd(&gcnt[b], 1.f);
}

__global__ void k_gdiv(float* gsum, const float* gcnt) {
  int b = blockIdx.x, j = threadIdx.x;
  gsum[b * 256 + j] /= fmaxf(gcnt[b], 1.f);
}

__global__ void k_gout(const float* __restrict__ g2, const float* __restrict__ gW2,
                       const float* __restrict__ gb2, float* __restrict__ out) {
  int b = threadIdx.x;
  if (b >= 64) return;
  float s = gb2[0];
  for (int j = 0; j < 256; ++j) s += g2[b * 256 + j] * gW2[j];
  out[b] = s;
}

// ------------------------------------------------------------------- launch
extern "C" void kernel_launch(void* const* d_in, const int* in_sizes, int n_in,
                              void* d_out, int out_size, void* d_ws, size_t ws_size,
                              hipStream_t stream) {
  const float* coords = (const float*)d_in[0];
  const int* atomids = (const int*)d_in[1];
  const int* ei = (const int*)d_in[2];
  const int* batch = (const int*)d_in[3];
  const float* emb = (const float*)d_in[5];
  const float* keW1 = (const float*)d_in[6];
  const float* keb1 = (const float*)d_in[7];
  const float* keW2 = (const float*)d_in[8];
  const float* keb2 = (const float*)d_in[9];
  const float* keng = (const float*)d_in[10];
  const float* kenb = (const float*)d_in[11];
  const float* kn1g = (const float*)d_in[12];
  const float* kn1b = (const float*)d_in[13];
  const float* knW1 = (const float*)d_in[14];
  const float* knb1 = (const float*)d_in[15];
  const float* knW2 = (const float*)d_in[16];
  const float* knb2 = (const float*)d_in[17];
  const float* kn2g = (const float*)d_in[18];
  const float* kn2b = (const float*)d_in[19];
  const float* fW0 = (const float*)d_in[20];
  const float* fb0 = (const float*)d_in[21];
  const float* fW1 = (const float*)d_in[22];
  const float* fb1 = (const float*)d_in[23];
  const float* fW2 = (const float*)d_in[24];
  const float* fb2 = (const float*)d_in[25];
  const float* gW0 = (const float*)d_in[26];
  const float* gb0 = (const float*)d_in[27];
  const float* gW1 = (const float*)d_in[28];
  const float* gb1 = (const float*)d_in[29];
  const float* gW2 = (const float*)d_in[30];
  const float* gb2 = (const float*)d_in[31];

  const int N = in_sizes[0] / 3;
  const int E = in_sizes[2] / 2;

  size_t off = 0;
  auto alloc = [&](size_t n) {
    float* p = (float*)d_ws + off;
    off += (n + 63) & ~(size_t)63;
    return p;
  };
  float* feats_all = alloc((size_t)N * 768);
  float* d_arr = alloc(E);
  float* deg = alloc(N);
  float* msum = alloc((size_t)N * 32);
  float* Abuf = alloc((size_t)N * 644);
  float* Bbuf = alloc((size_t)N * 644);
  float* gsum = alloc(64 * 256);
  float* gcnt = alloc(64);
  float* g1 = alloc(64 * 256);
  float* g2 = alloc(64 * 256);
  float* hcat = Abuf;                  // N x 160
  float* t1 = Abuf + (size_t)N * 160;  // N x 256
  float* t2 = Abuf + (size_t)N * 416;  // N x 128
  float* f1 = Bbuf;                    // N x 256
  float* f2 = Bbuf + (size_t)N * 256;  // N x 256

  unsigned short* ubase = (unsigned short*)(alloc(0));
  size_t uoff = 0;
  auto ualloc = [&](size_t n) {
    unsigned short* p = ubase + uoff;
    uoff += (n + 63) & ~(size_t)63;
    return p;
  };
  // per-layer strides
  const size_t sDst_ = 704 * 128, sSrc_ = 704 * 128, sEa_ = 704 * 64;
  const size_t sW2_ = 32 * 704, sN1_ = 256 * 160, sN2_ = 128 * 256;
  unsigned short* PdstH = ualloc(5 * sDst_); unsigned short* PdstL = ualloc(5 * sDst_);
  unsigned short* PsrcH = ualloc(5 * sSrc_); unsigned short* PsrcL = ualloc(5 * sSrc_);
  unsigned short* PeaH = ualloc(5 * sEa_);   unsigned short* PeaL = ualloc(5 * sEa_);
  unsigned short* PW2H = ualloc(5 * sW2_);   unsigned short* PW2L = ualloc(5 * sW2_);
  unsigned short* Pn1H = ualloc(5 * sN1_);   unsigned short* Pn1L = ualloc(5 * sN1_);
  unsigned short* Pn2H = ualloc(5 * sN2_);   unsigned short* Pn2L = ualloc(5 * sN2_);
  unsigned short* Pf0H = ualloc(256 * 768);  unsigned short* Pf0L = ualloc(256 * 768);
  unsigned short* Pf1H = ualloc(256 * 256);  unsigned short* Pf1L = ualloc(256 * 256);
  unsigned short* Pf2H = ualloc(256 * 256);  unsigned short* Pf2L = ualloc(256 * 256);
  unsigned short* Pg0H = ualloc(256 * 256);  unsigned short* Pg0L = ualloc(256 * 256);
  unsigned short* Pg1H = ualloc(256 * 256);  unsigned short* Pg1L = ualloc(256 * 256);

  // ---- prepacks (batched over 5 layers via gridDim.y)
  auto pp = [&](const float* W, size_t wStr, int ldw, int K, int Kpad, int Nc, int Npad,
                unsigned short* hi, unsigned short* lo, size_t oStr, int layers) {
    int total = Npad * Kpad;
    k_prepack<<<dim3((total + 255) / 256, layers), 256, 0, stream>>>(
        W, wStr, ldw, K, Kpad, Nc, Npad, hi, lo, oStr);
  };
  pp(keW1, (size_t)321 * 642, 642, 128, 128, 642, 704, PdstH, PdstL, sDst_, 5);
  pp(keW1 + 128 * 642, (size_t)321 * 642, 642, 128, 128, 642, 704, PsrcH, PsrcL, sSrc_, 5);
  pp(keW1 + 256 * 642, (size_t)321 * 642, 642, 64, 64, 642, 704, PeaH, PeaL, sEa_, 5);
  pp(keW2, (size_t)642 * 32, 32, 642, 704, 32, 32, PW2H, PW2L, sW2_, 5);
  pp(knW1, (size_t)160 * 256, 256, 160, 160, 256, 256, Pn1H, Pn1L, sN1_, 5);
  pp(knW2, (size_t)256 * 128, 128, 256, 256, 128, 128, Pn2H, Pn2L, sN2_, 5);
  pp(fW0, 0, 256, 768, 768, 256, 256, Pf0H, Pf0L, 0, 1);
  pp(fW1, 0, 256, 256, 256, 256, 256, Pf1H, Pf1L, 0, 1);
  pp(fW2, 0, 256, 256, 256, 256, 256, Pf2H, Pf2L, 0, 1);
  pp(gW0, 0, 256, 256, 256, 256, 256, Pg0H, Pg0L, 0, 1);
  pp(gW1, 0, 256, 256, 256, 256, 256, Pg1H, Pg1L, 0, 1);

  const int MT = (N + 63) / 64;
  k_gather<<<(N * 128 + 255) / 256, 256, 0, stream>>>(atomids, emb, feats_all, N);
  hipMemsetAsync(deg, 0, (size_t)N * sizeof(float), stream);
  k_edge_prep<<<(E + 255) / 256, 256, 0, stream>>>(coords, ei, E, d_arr, deg);

  for (int k = 0; k < 5; ++k) {
    gemm_mfma<<<dim3(MT, 11), 256, 0, stream>>>(
        feats_all + k * 128, 768, PdstH + k * sDst_, PdstL + k * sDst_, 128,
        keb1 + k * 642, Abuf, 644, N, 642, 128, 0, 0);
    gemm_mfma<<<dim3(MT, 11), 256, 0, stream>>>(
        feats_all + k * 128, 768, PsrcH + k * sSrc_, PsrcL + k * sSrc_, 128,
        nullptr, Bbuf, 644, N, 642, 128, 0, 0);
    hipMemsetAsync(msum, 0, (size_t)N * 32 * sizeof(float), stream);
    k_edge_mfma<<<(E + 63) / 64, 256, 0, stream>>>(
        Abuf, Bbuf, ei, E, d_arr,
        PeaH + k * sEa_, PeaL + k * sEa_,
        keW1 + (size_t)k * 321 * 642 + (size_t)320 * 642,
        PW2H + k * sW2_, PW2L + k * sW2_,
        keb2 + k * 32, keng + k * 32, kenb + k * 32, msum);
    k_node_ln<<<(N + 3) / 4, 256, 0, stream>>>(
        msum, deg, feats_all, k, kn1g + k * 128, kn1b + k * 128,
        keng + k * 32, kenb + k * 32, hcat, N);
    gemm_mfma<<<dim3(MT, 4), 256, 0, stream>>>(
        hcat, 160, Pn1H + k * sN1_, Pn1L + k * sN1_, 160,
        knb1 + k * 256, t1, 256, N, 256, 160, 1, 0);
    gemm_mfma<<<dim3(MT, 2), 256, 0, stream>>>(
        t1, 256, Pn2H + k * sN2_, Pn2L + k * sN2_, 256,
        knb2 + k * 128, t2, 128, N, 128, 256, 0, 0);
    k_node_resid<<<(N + 3) / 4, 256, 0, stream>>>(
        t2, feats_all, k, kn2g + k * 128, kn2b + k * 128, N);
  }

  gemm_mfma<<<dim3(MT, 4), 256, 0, stream>>>(
      feats_all, 768, Pf0H, Pf0L, 768, fb0, f1, 256, N, 256, 768, 1, 1);
  gemm_mfma<<<dim3(MT, 4), 256, 0, stream>>>(
      f1, 256, Pf1H, Pf1L, 256, fb1, f2, 256, N, 256, 256, 1, 0);
  gemm_mfma<<<dim3(MT, 4), 256, 0, stream>>>(
      f2, 256, Pf2H, Pf2L, 256, fb2, f1, 256, N, 256, 256, 1, 0);

  hipMemsetAsync(gsum, 0, 64 * 256 * sizeof(float), stream);
  hipMemsetAsync(gcnt, 0, 64 * sizeof(float), stream);
  k_pool<<<(N * 256 + 255) / 256, 256, 0, stream>>>(f1, batch, gsum, gcnt, N);
  k_gdiv<<<64, 256, 0, stream>>>(gsum, gcnt);
  gemm_mfma<<<dim3(1, 4), 256, 0, stream>>>(
      gsum, 256, Pg0H, Pg0L, 256, gb0, g1, 256, 64, 256, 256, 1, 0);
  gemm_mfma<<<dim3(1, 4), 256, 0, stream>>>(
      g1, 256, Pg1H, Pg1L, 256, gb1, g2, 256, 64, 256, 256, 1, 0);
  k_gout<<<1, 64, 0, stream>>>(g2, gW2, gb2, (float*)d_out);
}

// Round 3
// 2827.530 us; speedup vs baseline: 1.7392x; 1.0317x over previous
//
#include <hip/hip_runtime.h>
#include <cstdint>
#include <cstddef>

// DeltaNetMolecular R3: dst-sorted edges (counting sort) + pipelined fused edge
// kernel (stage(c+1) overlaps GEMM2(c)) + run-compressed msum atomics + M=128
// blocked bf16x3 MFMA GEMMs.

#define DEV __device__ __forceinline__

typedef __attribute__((ext_vector_type(8))) short bf16x8;
typedef __attribute__((ext_vector_type(4))) float f32x4;

DEV float siluf(float x) { return x / (1.f + __expf(-x)); }

DEV unsigned short f2bf(float f) {
  unsigned u = __float_as_uint(f);
  unsigned r = u + 0x7FFFu + ((u >> 16) & 1u);
  return (unsigned short)(r >> 16);
}
DEV float bf2f(unsigned short h) { return __uint_as_float(((unsigned)h) << 16); }

DEV f32x4 mfma16(bf16x8 a, bf16x8 b, f32x4 c) {
  return __builtin_amdgcn_mfma_f32_16x16x32_bf16(a, b, c, 0, 0, 0);
}

// ---------------------------------------------------------------- gather emb
__global__ __launch_bounds__(256) void k_gather(const int* __restrict__ atomids,
                                                const float* __restrict__ emb,
                                                float* __restrict__ feats_all, int N) {
  int idx = blockIdx.x * 256 + threadIdx.x;
  if (idx >= N * 128) return;
  int i = idx >> 7, j = idx & 127;
  feats_all[(size_t)i * 768 + j] = emb[atomids[i] * 128 + j];
}

// --------------------------------------------------- edge dist + dst histogram
__global__ __launch_bounds__(256) void k_edge_prep(const float* __restrict__ coords,
                                                   const int* __restrict__ ei, int E,
                                                   float* __restrict__ d_arr,
                                                   int* __restrict__ cnt) {
  int e = blockIdx.x * 256 + threadIdx.x;
  if (e >= E) return;
  int s = ei[e], t = ei[E + e];
  float dx = coords[3 * s + 0] - coords[3 * t + 0];
  float dy = coords[3 * s + 1] - coords[3 * t + 1];
  float dz = coords[3 * s + 2] - coords[3 * t + 2];
  d_arr[e] = dx * dx + dy * dy + dz * dz;
  atomicAdd(&cnt[t], 1);
}

// ------------------------------------------- single-block scan (N <= ~64K ok)
__global__ __launch_bounds__(1024) void k_scan(const int* __restrict__ cnt, int N,
                                               int* __restrict__ cursor,
                                               float* __restrict__ degf) {
  __shared__ int s[1024];
  __shared__ int carry;
  if (threadIdx.x == 0) carry = 0;
  __syncthreads();
  for (int base = 0; base < N; base += 1024) {
    int i = base + threadIdx.x;
    int v = (i < N) ? cnt[i] : 0;
    s[threadIdx.x] = v;
    __syncthreads();
    for (int off = 1; off < 1024; off <<= 1) {
      int add = (threadIdx.x >= off) ? s[threadIdx.x - off] : 0;
      __syncthreads();
      s[threadIdx.x] += add;
      __syncthreads();
    }
    if (i < N) {
      cursor[i] = s[threadIdx.x] - v + carry;
      degf[i] = fmaxf((float)v, 1.f);
    }
    __syncthreads();
    if (threadIdx.x == 0) carry += s[1023];
    __syncthreads();
  }
}

// ------------------------------------------------------- scatter sorted edges
__global__ __launch_bounds__(256) void k_scatter(const int* __restrict__ ei, int E,
                                                 const float* __restrict__ d_arr,
                                                 int* __restrict__ cursor,
                                                 int* __restrict__ ssrc,
                                                 int* __restrict__ sdst,
                                                 float* __restrict__ sd) {
  int e = blockIdx.x * 256 + threadIdx.x;
  if (e >= E) return;
  int s = ei[e], t = ei[E + e];
  int p = atomicAdd(&cursor[t], 1);
  ssrc[p] = s;
  sdst[p] = t;
  sd[p] = d_arr[e];
}

// ----------------------------------------------------- weight prepack (hi/lo)
__global__ __launch_bounds__(256) void k_prepack(
    const float* __restrict__ W, size_t wStride, int ldw,
    int K, int Kpad, int Ncols, int Npad,
    unsigned short* __restrict__ hi, unsigned short* __restrict__ lo, size_t oStride) {
  int idx = blockIdx.x * 256 + threadIdx.x;
  int total = Npad * Kpad;
  if (idx >= total) return;
  W += blockIdx.y * wStride;
  hi += blockIdx.y * oStride;
  lo += blockIdx.y * oStride;
  int n = idx / Kpad, k = idx - n * Kpad;
  float v = (n < Ncols && k < K) ? W[(size_t)k * ldw + n] : 0.f;
  unsigned short h = f2bf(v);
  hi[idx] = h;
  lo[idx] = f2bf(v - bf2f(h));
}

// ------------------------------------------- generic bf16x3 MFMA GEMM (M=128)
__global__ __launch_bounds__(256) void gemm_mfma(
    const float* __restrict__ A, int lda,
    const unsigned short* __restrict__ Bhi, const unsigned short* __restrict__ Blo,
    int Kpad, const float* __restrict__ bias,
    float* __restrict__ C, int ldc,
    int M, int Ncols, int K, int actOut, int actA) {
  const int t = threadIdx.x;
  const int wave = t >> 6, lane = t & 63;
  const int nl = lane & 15, quad = lane >> 4;
  const int bm = blockIdx.x * 128 + wave * 32;
  const int bn = blockIdx.y * 64;
  f32x4 zero = {0.f, 0.f, 0.f, 0.f};
  f32x4 acc[2][4] = {{zero, zero, zero, zero}, {zero, zero, zero, zero}};
  for (int kb = 0; kb < K; kb += 32) {
    bf16x8 ah[2], al[2];
#pragma unroll
    for (int h = 0; h < 2; ++h) {
      int row = bm + h * 16 + nl;
      float av[8];
      if (row < M) {
        const float* ap = A + (size_t)row * lda + kb + quad * 8;
        f32x4 v0 = *(const f32x4*)ap;
        f32x4 v1 = *(const f32x4*)(ap + 4);
        av[0] = v0.x; av[1] = v0.y; av[2] = v0.z; av[3] = v0.w;
        av[4] = v1.x; av[5] = v1.y; av[6] = v1.z; av[7] = v1.w;
        if (actA) {
#pragma unroll
          for (int j = 0; j < 8; ++j) av[j] = siluf(av[j]);
        }
      } else {
#pragma unroll
        for (int j = 0; j < 8; ++j) av[j] = 0.f;
      }
#pragma unroll
      for (int j = 0; j < 8; ++j) {
        unsigned short hh = f2bf(av[j]);
        ah[h][j] = (short)hh;
        al[h][j] = (short)f2bf(av[j] - bf2f(hh));
      }
    }
#pragma unroll
    for (int tn = 0; tn < 4; ++tn) {
      size_t boff = (size_t)(bn + tn * 16 + nl) * Kpad + kb + quad * 8;
      bf16x8 bh = *(const bf16x8*)(Bhi + boff);
      bf16x8 bl = *(const bf16x8*)(Blo + boff);
#pragma unroll
      for (int h = 0; h < 2; ++h) {
        acc[h][tn] = mfma16(ah[h], bh, acc[h][tn]);
        acc[h][tn] = mfma16(ah[h], bl, acc[h][tn]);
        acc[h][tn] = mfma16(al[h], bh, acc[h][tn]);
      }
    }
  }
#pragma unroll
  for (int h = 0; h < 2; ++h) {
#pragma unroll
    for (int tn = 0; tn < 4; ++tn) {
      int c = bn + tn * 16 + nl;
      if (c >= Ncols) continue;
      float bv = bias ? bias[c] : 0.f;
#pragma unroll
      for (int r = 0; r < 4; ++r) {
        int rr = bm + h * 16 + quad * 4 + r;
        if (rr >= M) continue;
        float v = acc[h][tn][r] + bv;
        if (actOut) v = siluf(v);
        C[(size_t)rr * ldc + c] = v;
      }
    }
  }
}

// ----------------------------------- fused edge kernel (sorted, pipelined)
__global__ __launch_bounds__(256) void k_edge_mfma(
    const float* __restrict__ Ab, const float* __restrict__ Bb,  // [N,644]
    const int* __restrict__ ssrc, const int* __restrict__ sdst,
    const float* __restrict__ sd_g, int E,
    const unsigned short* __restrict__ WeaThi, const unsigned short* __restrict__ WeaTlo,
    const float* __restrict__ Wea64,
    const unsigned short* __restrict__ W2Thi, const unsigned short* __restrict__ W2Tlo,
    const float* __restrict__ b2v,
    const float* __restrict__ eng, const float* __restrict__ enb,
    float* __restrict__ msum) {
  __shared__ float sAB[64 * 68];
  __shared__ float sH[64 * 76];
  __shared__ float sD[64];
  __shared__ int sSrc[64], sDst[64];

  const int t = threadIdx.x;
  const int wave = t >> 6, lane = t & 63;
  const int nl = lane & 15, quad = lane >> 4;
  const int e0 = blockIdx.x * 64;

  if (t < 64) {
    int e = e0 + t;
    sSrc[t] = (e < E) ? ssrc[e] : 0;
    sDst[t] = (e < E) ? sdst[e] : 0;
    sD[t] = (e < E) ? sd_g[e] : 0.f;
  }
  __syncthreads();

  // ea A-frags (register-resident)
  bf16x8 eaHi[2], eaLo[2];
  {
    float d = sD[wave * 16 + nl];
#pragma unroll
    for (int ks = 0; ks < 2; ++ks) {
#pragma unroll
      for (int j = 0; j < 8; ++j) {
        int k = ks * 32 + quad * 8 + j;
        float arg = d * exp2f(-(float)(k & 31));
        float v = (k < 32) ? sinf(arg) : cosf(arg);
        unsigned short h = f2bf(v);
        eaHi[ks][j] = (short)h;
        eaLo[ks][j] = (short)f2bf(v - bf2f(h));
      }
    }
  }

  f32x4 zero = {0.f, 0.f, 0.f, 0.f};
  f32x4 macc[2] = {zero, zero};

  auto stage = [&](int cc) {
    const int jb = cc * 64;
    for (int idx = t; idx < 64 * 16; idx += 256) {
      int e = idx >> 4, p = idx & 15;
      int col = jb + p * 4;
      float d = sD[e];
      const float* ap = Ab + (size_t)sDst[e] * 644 + col;
      const float* bp = Bb + (size_t)sSrc[e] * 644 + col;
      float o[4];
      if (col + 3 < 642) {
        f32x4 va = *(const f32x4*)ap;
        f32x4 vb = *(const f32x4*)bp;
        f32x4 vw = *(const f32x4*)(Wea64 + col);
        o[0] = va.x + vb.x + d * vw.x;
        o[1] = va.y + vb.y + d * vw.y;
        o[2] = va.z + vb.z + d * vw.z;
        o[3] = va.w + vb.w + d * vw.w;
      } else {
#pragma unroll
        for (int u = 0; u < 4; ++u)
          o[u] = (col + u < 642) ? (ap[u] + bp[u] + d * Wea64[col + u]) : 0.f;
      }
#pragma unroll
      for (int u = 0; u < 4; ++u) sAB[e * 68 + p * 4 + u] = o[u];
    }
  };

  auto gemm1 = [&](int cc) {
    const int jb = cc * 64;
    f32x4 acc1[4] = {zero, zero, zero, zero};
#pragma unroll
    for (int tn = 0; tn < 4; ++tn) {
      size_t base = (size_t)(jb + tn * 16 + nl) * 64 + quad * 8;
#pragma unroll
      for (int ks = 0; ks < 2; ++ks) {
        bf16x8 bh = *(const bf16x8*)(WeaThi + base + ks * 32);
        bf16x8 bl = *(const bf16x8*)(WeaTlo + base + ks * 32);
        acc1[tn] = mfma16(eaHi[ks], bh, acc1[tn]);
        acc1[tn] = mfma16(eaHi[ks], bl, acc1[tn]);
        acc1[tn] = mfma16(eaLo[ks], bh, acc1[tn]);
      }
    }
#pragma unroll
    for (int tn = 0; tn < 4; ++tn) {
#pragma unroll
      for (int r = 0; r < 4; ++r) {
        int e = wave * 16 + quad * 4 + r;
        int colc = tn * 16 + nl;
        sH[e * 76 + colc] = siluf(acc1[tn][r] + sAB[e * 68 + colc]);
      }
    }
  };

  auto gemm2 = [&](int cc) {
    const int jb = cc * 64;
#pragma unroll
    for (int ks = 0; ks < 2; ++ks) {
      const float* hp = &sH[(wave * 16 + nl) * 76 + ks * 32 + quad * 8];
      f32x4 h0 = *(const f32x4*)hp;
      f32x4 h1 = *(const f32x4*)(hp + 4);
      float hv[8] = {h0.x, h0.y, h0.z, h0.w, h1.x, h1.y, h1.z, h1.w};
      bf16x8 ah, al;
#pragma unroll
      for (int j = 0; j < 8; ++j) {
        unsigned short hh = f2bf(hv[j]);
        ah[j] = (short)hh;
        al[j] = (short)f2bf(hv[j] - bf2f(hh));
      }
#pragma unroll
      for (int tn = 0; tn < 2; ++tn) {
        size_t base = (size_t)(tn * 16 + nl) * 704 + jb + ks * 32 + quad * 8;
        bf16x8 bh = *(const bf16x8*)(W2Thi + base);
        bf16x8 bl = *(const bf16x8*)(W2Tlo + base);
        macc[tn] = mfma16(ah, bh, macc[tn]);
        macc[tn] = mfma16(ah, bl, macc[tn]);
        macc[tn] = mfma16(al, bh, macc[tn]);
      }
    }
  };

  // pipelined main loop: stage(c+1) overlaps gemm2(c)
  stage(0);
  __syncthreads();
  gemm1(0);
  for (int c = 0; c < 11; ++c) {
    __syncthreads();               // sH(c) ready; sAB(c) consumed
    if (c + 1 < 11) stage(c + 1);  // global gathers overlap GEMM2 MFMAs
    gemm2(c);
    if (c + 1 < 11) {
      __syncthreads();             // sAB(c+1) ready; sH free
      gemm1(c + 1);
    }
  }

  // epilogue: bias + silu + LN(32), stage to LDS, run-compressed atomics
  __syncthreads();
  float* sM = sAB;
  float g0 = eng[nl], g1v = eng[16 + nl], bb0 = enb[nl], bb1 = enb[16 + nl];
  float bi0 = b2v[nl], bi1 = b2v[16 + nl];
#pragma unroll
  for (int r = 0; r < 4; ++r) {
    float v0 = siluf(macc[0][r] + bi0);
    float v1 = siluf(macc[1][r] + bi1);
    float s = v0 + v1;
    float ss = v0 * v0 + v1 * v1;
#pragma unroll
    for (int m = 1; m < 16; m <<= 1) {
      s += __shfl_xor(s, m, 16);
      ss += __shfl_xor(ss, m, 16);
    }
    float mu = s * (1.f / 32.f);
    float var = ss * (1.f / 32.f) - mu * mu;
    float rs = rsqrtf(var + 1e-5f);
    int eb = wave * 16 + quad * 4 + r;
    sM[eb * 33 + nl] = (v0 - mu) * rs * g0 + bb0;
    sM[eb * 33 + 16 + nl] = (v1 - mu) * rs * g1v + bb1;
  }
  __syncthreads();
  {
    int col = t & 31, seg = t >> 5;
    float acc = 0.f;
    int cur = -1;
#pragma unroll
    for (int i = 0; i < 8; ++i) {
      int e = seg * 8 + i;
      int dn = (e0 + e < E) ? sDst[e] : -1;
      if (dn != cur) {
        if (cur >= 0) atomicAdd(&msum[(size_t)cur * 32 + col], acc);
        acc = 0.f;
        cur = dn;
      }
      if (dn >= 0) acc += sM[e * 33 + col];
    }
    if (cur >= 0) atomicAdd(&msum[(size_t)cur * 32 + col], acc);
  }
}

// --------------------------------------------- node-side LN + concat builder
__global__ __launch_bounds__(256) void k_node_ln(
    const float* __restrict__ msum, const float* __restrict__ deg,
    const float* __restrict__ featsAll, int k,
    const float* __restrict__ n1g, const float* __restrict__ n1b,
    const float* __restrict__ eng, const float* __restrict__ enb,
    float* __restrict__ hcat, int N) {
  int node = blockIdx.x * 4 + (threadIdx.x >> 6);
  int lane = threadIdx.x & 63;
  if (node >= N) return;
  const float* fr = featsAll + (size_t)node * 768 + k * 128;
  float x0 = fr[lane], x1 = fr[64 + lane];
  float s = x0 + x1;
#pragma unroll
  for (int m = 1; m < 64; m <<= 1) s += __shfl_xor(s, m, 64);
  float mu = s * (1.f / 128.f);
  float d0 = x0 - mu, d1 = x1 - mu;
  float v = d0 * d0 + d1 * d1;
#pragma unroll
  for (int m = 1; m < 64; m <<= 1) v += __shfl_xor(v, m, 64);
  float rstd = rsqrtf(v * (1.f / 128.f) + 1e-5f);
  float* hr = hcat + (size_t)node * 160;
  hr[lane] = d0 * rstd * n1g[lane] + n1b[lane];
  hr[64 + lane] = d1 * rstd * n1g[64 + lane] + n1b[64 + lane];
  float dg = deg[node];
  int col = lane & 31;
  float y = msum[(size_t)node * 32 + col] / dg;
  float sy = y;
#pragma unroll
  for (int m = 1; m < 32; m <<= 1) sy += __shfl_xor(sy, m, 32);
  float mu2 = sy * (1.f / 32.f);
  float dy = y - mu2;
  float vy = dy * dy;
#pragma unroll
  for (int m = 1; m < 32; m <<= 1) vy += __shfl_xor(vy, m, 32);
  float rstd2 = rsqrtf(vy * (1.f / 32.f) + 1e-5f);
  if (lane < 32) hr[128 + col] = dy * rstd2 * eng[col] + enb[col];
}

// ------------------------------------------------ node residual + final LN
__global__ __launch_bounds__(256) void k_node_resid(
    const float* __restrict__ t2, float* __restrict__ featsAll, int k,
    const float* __restrict__ n2g, const float* __restrict__ n2b, int N) {
  int node = blockIdx.x * 4 + (threadIdx.x >> 6);
  int lane = threadIdx.x & 63;
  if (node >= N) return;
  const float* tr = t2 + (size_t)node * 128;
  float x0 = tr[lane], x1 = tr[64 + lane];
  float s = x0 + x1;
#pragma unroll
  for (int m = 1; m < 64; m <<= 1) s += __shfl_xor(s, m, 64);
  float mu = s * (1.f / 128.f);
  float d0 = x0 - mu, d1 = x1 - mu;
  float v = d0 * d0 + d1 * d1;
#pragma unroll
  for (int m = 1; m < 64; m <<= 1) v += __shfl_xor(v, m, 64);
  float rstd = rsqrtf(v * (1.f / 128.f) + 1e-5f);
  const float* fk = featsAll + (size_t)node * 768 + k * 128;
  float* fo = featsAll + (size_t)node * 768 + (k + 1) * 128;
  fo[lane] = fk[lane] + d0 * rstd * n2g[lane] + n2b[lane];
  fo[64 + lane] = fk[64 + lane] + d1 * rstd * n2g[64 + lane] + n2b[64 + lane];
}

// ----------------------------------------------------------- graph pooling
__global__ __launch_bounds__(256) void k_pool(const float* __restrict__ f,
                                              const int* __restrict__ batch,
                                              float* __restrict__ gsum,
                                              float* __restrict__ gcnt, int N) {
  int idx = blockIdx.x * 256 + threadIdx.x;
  if (idx >= N * 256) return;
  int i = idx >> 8, j = idx & 255;
  int b = batch[i];
  atomicAdd(&gsum[b * 256 + j], f[idx]);
  if (j == 0) atomicAdd(&gcnt[b], 1.f);
}

__global__ void k_gdiv(float* gsum, const float* gcnt) {
  int b = blockIdx.x, j = threadIdx.x;
  gsum[b * 256 + j] /= fmaxf(gcnt[b], 1.f);
}

__global__ void k_gout(const float* __restrict__ g2, const float* __restrict__ gW2,
                       const float* __restrict__ gb2, float* __restrict__ out) {
  int b = threadIdx.x;
  if (b >= 64) return;
  float s = gb2[0];
  for (int j = 0; j < 256; ++j) s += g2[b * 256 + j] * gW2[j];
  out[b] = s;
}

// ------------------------------------------------------------------- launch
extern "C" void kernel_launch(void* const* d_in, const int* in_sizes, int n_in,
                              void* d_out, int out_size, void* d_ws, size_t ws_size,
                              hipStream_t stream) {
  const float* coords = (const float*)d_in[0];
  const int* atomids = (const int*)d_in[1];
  const int* ei = (const int*)d_in[2];
  const int* batch = (const int*)d_in[3];
  const float* emb = (const float*)d_in[5];
  const float* keW1 = (const float*)d_in[6];
  const float* keb1 = (const float*)d_in[7];
  const float* keW2 = (const float*)d_in[8];
  const float* keb2 = (const float*)d_in[9];
  const float* keng = (const float*)d_in[10];
  const float* kenb = (const float*)d_in[11];
  const float* kn1g = (const float*)d_in[12];
  const float* kn1b = (const float*)d_in[13];
  const float* knW1 = (const float*)d_in[14];
  const float* knb1 = (const float*)d_in[15];
  const float* knW2 = (const float*)d_in[16];
  const float* knb2 = (const float*)d_in[17];
  const float* kn2g = (const float*)d_in[18];
  const float* kn2b = (const float*)d_in[19];
  const float* fW0 = (const float*)d_in[20];
  const float* fb0 = (const float*)d_in[21];
  const float* fW1 = (const float*)d_in[22];
  const float* fb1 = (const float*)d_in[23];
  const float* fW2 = (const float*)d_in[24];
  const float* fb2 = (const float*)d_in[25];
  const float* gW0 = (const float*)d_in[26];
  const float* gb0 = (const float*)d_in[27];
  const float* gW1 = (const float*)d_in[28];
  const float* gb1 = (const float*)d_in[29];
  const float* gW2 = (const float*)d_in[30];
  const float* gb2 = (const float*)d_in[31];

  const int N = in_sizes[0] / 3;
  const int E = in_sizes[2] / 2;

  size_t off = 0;
  auto alloc = [&](size_t n) {
    float* p = (float*)d_ws + off;
    off += (n + 63) & ~(size_t)63;
    return p;
  };
  float* feats_all = alloc((size_t)N * 768);
  float* d_arr = alloc(E);
  float* degf = alloc(N);
  float* msum = alloc((size_t)N * 32);
  float* Abuf = alloc((size_t)N * 644);
  float* Bbuf = alloc((size_t)N * 644);
  float* gsum = alloc(64 * 256);
  float* gcnt = alloc(64);
  float* g1 = alloc(64 * 256);
  float* g2 = alloc(64 * 256);
  int* cnt = (int*)alloc(N);
  int* cursor = (int*)alloc(N);
  int* ssrc = (int*)alloc(E);
  int* sdst = (int*)alloc(E);
  float* sd = alloc(E);
  float* hcat = Abuf;                  // N x 160
  float* t1 = Abuf + (size_t)N * 160;  // N x 256
  float* t2 = Abuf + (size_t)N * 416;  // N x 128
  float* f1 = Bbuf;                    // N x 256
  float* f2 = Bbuf + (size_t)N * 256;  // N x 256

  unsigned short* ubase = (unsigned short*)(alloc(0));
  size_t uoff = 0;
  auto ualloc = [&](size_t n) {
    unsigned short* p = ubase + uoff;
    uoff += (n + 63) & ~(size_t)63;
    return p;
  };
  const size_t sDst_ = 704 * 128, sSrc_ = 704 * 128, sEa_ = 704 * 64;
  const size_t sW2_ = 32 * 704, sN1_ = 256 * 160, sN2_ = 128 * 256;
  unsigned short* PdstH = ualloc(5 * sDst_); unsigned short* PdstL = ualloc(5 * sDst_);
  unsigned short* PsrcH = ualloc(5 * sSrc_); unsigned short* PsrcL = ualloc(5 * sSrc_);
  unsigned short* PeaH = ualloc(5 * sEa_);   unsigned short* PeaL = ualloc(5 * sEa_);
  unsigned short* PW2H = ualloc(5 * sW2_);   unsigned short* PW2L = ualloc(5 * sW2_);
  unsigned short* Pn1H = ualloc(5 * sN1_);   unsigned short* Pn1L = ualloc(5 * sN1_);
  unsigned short* Pn2H = ualloc(5 * sN2_);   unsigned short* Pn2L = ualloc(5 * sN2_);
  unsigned short* Pf0H = ualloc(256 * 768);  unsigned short* Pf0L = ualloc(256 * 768);
  unsigned short* Pf1H = ualloc(256 * 256);  unsigned short* Pf1L = ualloc(256 * 256);
  unsigned short* Pf2H = ualloc(256 * 256);  unsigned short* Pf2L = ualloc(256 * 256);
  unsigned short* Pg0H = ualloc(256 * 256);  unsigned short* Pg0L = ualloc(256 * 256);
  unsigned short* Pg1H = ualloc(256 * 256);  unsigned short* Pg1L = ualloc(256 * 256);

  auto pp = [&](const float* W, size_t wStr, int ldw, int K, int Kpad, int Nc, int Npad,
                unsigned short* hi, unsigned short* lo, size_t oStr, int layers) {
    int total = Npad * Kpad;
    k_prepack<<<dim3((total + 255) / 256, layers), 256, 0, stream>>>(
        W, wStr, ldw, K, Kpad, Nc, Npad, hi, lo, oStr);
  };
  pp(keW1, (size_t)321 * 642, 642, 128, 128, 642, 704, PdstH, PdstL, sDst_, 5);
  pp(keW1 + 128 * 642, (size_t)321 * 642, 642, 128, 128, 642, 704, PsrcH, PsrcL, sSrc_, 5);
  pp(keW1 + 256 * 642, (size_t)321 * 642, 642, 64, 64, 642, 704, PeaH, PeaL, sEa_, 5);
  pp(keW2, (size_t)642 * 32, 32, 642, 704, 32, 32, PW2H, PW2L, sW2_, 5);
  pp(knW1, (size_t)160 * 256, 256, 160, 160, 256, 256, Pn1H, Pn1L, sN1_, 5);
  pp(knW2, (size_t)256 * 128, 128, 256, 256, 128, 128, Pn2H, Pn2L, sN2_, 5);
  pp(fW0, 0, 256, 768, 768, 256, 256, Pf0H, Pf0L, 0, 1);
  pp(fW1, 0, 256, 256, 256, 256, 256, Pf1H, Pf1L, 0, 1);
  pp(fW2, 0, 256, 256, 256, 256, 256, Pf2H, Pf2L, 0, 1);
  pp(gW0, 0, 256, 256, 256, 256, 256, Pg0H, Pg0L, 0, 1);
  pp(gW1, 0, 256, 256, 256, 256, 256, Pg1H, Pg1L, 0, 1);

  // ---- edge sort by dst (counting sort)
  k_gather<<<(N * 128 + 255) / 256, 256, 0, stream>>>(atomids, emb, feats_all, N);
  hipMemsetAsync(cnt, 0, (size_t)N * sizeof(int), stream);
  k_edge_prep<<<(E + 255) / 256, 256, 0, stream>>>(coords, ei, E, d_arr, cnt);
  k_scan<<<1, 1024, 0, stream>>>(cnt, N, cursor, degf);
  k_scatter<<<(E + 255) / 256, 256, 0, stream>>>(ei, E, d_arr, cursor, ssrc, sdst, sd);

  const int MT = (N + 127) / 128;
  for (int k = 0; k < 5; ++k) {
    gemm_mfma<<<dim3(MT, 11), 256, 0, stream>>>(
        feats_all + k * 128, 768, PdstH + k * sDst_, PdstL + k * sDst_, 128,
        keb1 + k * 642, Abuf, 644, N, 642, 128, 0, 0);
    gemm_mfma<<<dim3(MT, 11), 256, 0, stream>>>(
        feats_all + k * 128, 768, PsrcH + k * sSrc_, PsrcL + k * sSrc_, 128,
        nullptr, Bbuf, 644, N, 642, 128, 0, 0);
    hipMemsetAsync(msum, 0, (size_t)N * 32 * sizeof(float), stream);
    k_edge_mfma<<<(E + 63) / 64, 256, 0, stream>>>(
        Abuf, Bbuf, ssrc, sdst, sd, E,
        PeaH + k * sEa_, PeaL + k * sEa_,
        keW1 + (size_t)k * 321 * 642 + (size_t)320 * 642,
        PW2H + k * sW2_, PW2L + k * sW2_,
        keb2 + k * 32, keng + k * 32, kenb + k * 32, msum);
    k_node_ln<<<(N + 3) / 4, 256, 0, stream>>>(
        msum, degf, feats_all, k, kn1g + k * 128, kn1b + k * 128,
        keng + k * 32, kenb + k * 32, hcat, N);
    gemm_mfma<<<dim3(MT, 4), 256, 0, stream>>>(
        hcat, 160, Pn1H + k * sN1_, Pn1L + k * sN1_, 160,
        knb1 + k * 256, t1, 256, N, 256, 160, 1, 0);
    gemm_mfma<<<dim3(MT, 2), 256, 0, stream>>>(
        t1, 256, Pn2H + k * sN2_, Pn2L + k * sN2_, 256,
        knb2 + k * 128, t2, 128, N, 128, 256, 0, 0);
    k_node_resid<<<(N + 3) / 4, 256, 0, stream>>>(
        t2, feats_all, k, kn2g + k * 128, kn2b + k * 128, N);
  }

  gemm_mfma<<<dim3(MT, 4), 256, 0, stream>>>(
      feats_all, 768, Pf0H, Pf0L, 768, fb0, f1, 256, N, 256, 768, 1, 1);
  gemm_mfma<<<dim3(MT, 4), 256, 0, stream>>>(
      f1, 256, Pf1H, Pf1L, 256, fb1, f2, 256, N, 256, 256, 1, 0);
  gemm_mfma<<<dim3(MT, 4), 256, 0, stream>>>(
      f2, 256, Pf2H, Pf2L, 256, fb2, f1, 256, N, 256, 256, 1, 0);

  hipMemsetAsync(gsum, 0, 64 * 256 * sizeof(float), stream);
  hipMemsetAsync(gcnt, 0, 64 * sizeof(float), stream);
  k_pool<<<(N * 256 + 255) / 256, 256, 0, stream>>>(f1, batch, gsum, gcnt, N);
  k_gdiv<<<64, 256, 0, stream>>>(gsum, gcnt);
  gemm_mfma<<<dim3(1, 4), 256, 0, stream>>>(
      gsum, 256, Pg0H, Pg0L, 256, gb0, g1, 256, 64, 256, 256, 1, 0);
  gemm_mfma<<<dim3(1, 4), 256, 0, stream>>>(
      g1, 256, Pg1H, Pg1L, 256, gb1, g2, 256, 64, 256, 256, 1, 0);
  k_gout<<<1, 64, 0, stream>>>(g2, gW2, gb2, (float*)d_out);
}